// Round 8
// baseline (343.709 us; speedup 1.0000x reference)
//
#include <hip/hip_runtime.h>
#include <hip/hip_bf16.h>

#define BATCH  16384
#define SLOPE  0.2f

typedef __attribute__((ext_vector_type(8))) short bf16x8;
typedef __attribute__((ext_vector_type(4))) float f32x4;

// ws layout (bf16 element offsets), weights TRANSPOSED as [N][K]; s/t contiguous.
#define OFF_SW0T 0         // [128][2048]
#define OFF_TW0T 262144
#define OFF_SW1T 524288    // [128][128]
#define OFF_TW1T 540672
#define OFF_SW2T 557056    // [2048][128]
#define OFF_TW2T 819200

__device__ __forceinline__ unsigned short f2bf(float f) {
    unsigned int u = __float_as_uint(f);
    u += 0x7FFFu + ((u >> 16) & 1u);   // round-to-nearest-even
    return (unsigned short)(u >> 16);
}

__global__ void conv_w(const float* __restrict__ sW0, const float* __restrict__ sW1,
                       const float* __restrict__ sW2, const float* __restrict__ tW0,
                       const float* __restrict__ tW1, const float* __restrict__ tW2,
                       unsigned short* __restrict__ ws) {
    const int total = 262144 + 16384 + 262144;
    for (int i = blockIdx.x * blockDim.x + threadIdx.x; i < total;
         i += gridDim.x * blockDim.x) {
        if (i < 262144) {                    // W0 [2048][128] -> [128][2048]
            int k = i >> 7, n = i & 127;
            ws[OFF_SW0T + n * 2048 + k] = f2bf(sW0[i]);
            ws[OFF_TW0T + n * 2048 + k] = f2bf(tW0[i]);
        } else if (i < 262144 + 16384) {     // W1 [128][128] -> transpose
            int j = i - 262144;
            int k = j >> 7, n = j & 127;
            ws[OFF_SW1T + n * 128 + k] = f2bf(sW1[j]);
            ws[OFF_TW1T + n * 128 + k] = f2bf(tW1[j]);
        } else {                             // W2 [128][2048] -> [2048][128]
            int j = i - (262144 + 16384);
            int k = j >> 11, n = j & 2047;
            ws[OFF_SW2T + n * 128 + k] = f2bf(sW2[j]);
            ws[OFF_TW2T + n * 128 + k] = f2bf(tW2[j]);
        }
    }
}

// ---------------- K1: layers 0+1, h1 -> tail of f rows ----------------
// BM=16. Reads z rows directly (float4), extracts A in-register. h1 (bf16,
// 256 per row = 512 B) stored at f-row bytes [12288, 12800) — read by K2
// (same rows) before K2 overwrites that span at its chunk 24.
__global__ __launch_bounds__(256, 4) void layers01(
    const float* __restrict__ z,
    const unsigned short* __restrict__ ws,
    char* __restrict__ fbytes) {

    // [0,4096) Az dbuf 2 x [16 rows][128 B] swz | [4096,20480) HA [16][256] u16 swz
    __shared__ __align__(16) unsigned char LDSbuf[20480];
    unsigned short* HA = (unsigned short*)(LDSbuf + 4096);

    const int tid  = threadIdx.x;
    const int wave = tid >> 6;
    const int lane = tid & 63;
    const int l15  = lane & 15;
    const int l4   = lane >> 4;
    const int brow = blockIdx.x * 16;

    const float4* __restrict__ zf4 = (const float4*)z;

    const int srow = tid >> 4;      // staging row 0..15
    const int slot = tid & 15;      // 4 A-cols per slot
    const int spar = slot >> 3;     // lattice-row parity of this slot

    float4 pre[2];
    auto ldz = [&](int c) {
        const float4* p = zf4 + (size_t)(brow + srow) * 1024 + c * 32 + slot * 2;
        pre[0] = p[0]; pre[1] = p[1];
    };
    auto wrz = [&](int buf) {
        union { unsigned long long q; unsigned short s[4]; } u;
        u.s[0] = f2bf(spar ? pre[0].y : pre[0].x);
        u.s[1] = f2bf(spar ? pre[0].w : pre[0].z);
        u.s[2] = f2bf(spar ? pre[1].y : pre[1].x);
        u.s[3] = f2bf(spar ? pre[1].w : pre[1].z);
        *(unsigned long long*)(LDSbuf + buf * 2048 + srow * 128 +
                               ((slot * 8) ^ ((srow & 7) << 4))) = u.q;
    };

    ldz(0);
    wrz(0);
    __syncthreads();

    f32x4 acc0[4] = {};   // [n2]
    #pragma unroll 1
    for (int c = 0; c < 32; ++c) {
        if (c < 31) ldz(c + 1);                       // issue early (T14)
        const char* Az = (const char*)(LDSbuf + (c & 1) * 2048);
        bf16x8 af[2];
        #pragma unroll
        for (int k2 = 0; k2 < 2; ++k2)
            af[k2] = *(const bf16x8*)(Az + l15 * 128 +
                       ((k2 * 64 + l4 * 16) ^ ((l15 & 7) << 4)));
        #pragma unroll
        for (int n2 = 0; n2 < 4; ++n2) {
            const size_t wb = (size_t)(wave * 64 + n2 * 16 + l15) * 2048 + c * 64 + l4 * 8;
            #pragma unroll
            for (int k2 = 0; k2 < 2; ++k2) {
                const bf16x8 w = *(const bf16x8*)&ws[OFF_SW0T + wb + k2 * 32];
                acc0[n2] = __builtin_amdgcn_mfma_f32_16x16x32_bf16(
                    af[k2], w, acc0[n2], 0, 0, 0);
            }
        }
        if (c < 31) wrz((c + 1) & 1);                 // write other buffer
        __syncthreads();
    }

    // leaky, h0 -> HA (swizzled)
    #pragma unroll
    for (int n2 = 0; n2 < 4; ++n2)
        #pragma unroll
        for (int r = 0; r < 4; ++r) {
            float v = acc0[n2][r];
            v = v > 0.0f ? v : SLOPE * v;
            const int row = l4 * 4 + r;
            const int col = wave * 64 + n2 * 16 + l15;
            HA[row * 256 + (col ^ ((row & 7) << 3))] = f2bf(v);
        }
    __syncthreads();

    // layer 1
    f32x4 acc1[4] = {};
    const int net1 = wave >> 1;
    #pragma unroll
    for (int k4 = 0; k4 < 4; ++k4) {
        const bf16x8 ahv = *(const bf16x8*)&HA[l15 * 256 +
            ((net1 * 128 + k4 * 32 + l4 * 8) ^ ((l15 & 7) << 3))];
        #pragma unroll
        for (int n2 = 0; n2 < 4; ++n2) {
            const bf16x8 w = *(const bf16x8*)&ws[OFF_SW1T +
                (size_t)(wave * 64 + n2 * 16 + l15) * 128 + k4 * 32 + l4 * 8];
            acc1[n2] = __builtin_amdgcn_mfma_f32_16x16x32_bf16(
                ahv, w, acc1[n2], 0, 0, 0);
        }
    }
    __syncthreads();   // all HA reads done before overwrite

    // leaky, h1 -> HA (same swizzled layout)
    #pragma unroll
    for (int n2 = 0; n2 < 4; ++n2)
        #pragma unroll
        for (int r = 0; r < 4; ++r) {
            float v = acc1[n2][r];
            v = v > 0.0f ? v : SLOPE * v;
            const int row = l4 * 4 + r;
            const int col = wave * 64 + n2 * 16 + l15;
            HA[row * 256 + (col ^ ((row & 7) << 3))] = f2bf(v);
        }
    __syncthreads();

    // store h1 -> f-row tail, coalesced 16B, unswizzling
    #pragma unroll
    for (int i = 0; i < 2; ++i) {
        const int s = tid + 256 * i;          // 0..511
        const int row = s >> 5, col16 = s & 31;
        const bf16x8 hv = *(const bf16x8*)(LDSbuf + 4096 + row * 512 +
                                           ((col16 ^ (row & 7)) << 4));
        *(bf16x8*)(fbytes + (size_t)(brow + row) * 16384 + 12288 + col16 * 16) = hv;
    }
}

// ---------------- K2: layer 2 + coupling epilogue ----------------
// BM=16, zero-LDS GEMM, barrier-free main loop. A-frags read from f-row tails
// (aliases f_out -> compiler must keep them in registers).
__global__ __launch_bounds__(256, 4) void layer2ep(
    const float* __restrict__ z,
    const float* __restrict__ s_b2,
    const float* __restrict__ t_b2,
    const unsigned short* __restrict__ ws,
    float* __restrict__ f_out,
    float* __restrict__ d_vec) {

    __shared__ float Dred[64];

    const int tid  = threadIdx.x;
    const int wave = tid >> 6;   // pair-quarter nq
    const int lane = tid & 63;
    const int l15  = lane & 15;
    const int l4   = lane >> 4;
    const int brow = blockIdx.x * 16;

    const char* fbytes = (const char*)f_out;
    const float2* __restrict__ zf2 = (const float2*)z;
    float2* ff2 = (float2*)f_out;

    // A-fragments: h1 rows brow..brow+16, both nets. 8 x bf16x8 = 32 VGPR.
    bf16x8 ahs[4], aht[4];
    {
        const char* p = fbytes + (size_t)(brow + l15) * 16384 + 12288 + l4 * 16;
        #pragma unroll
        for (int k4 = 0; k4 < 4; ++k4) {
            ahs[k4] = *(const bf16x8*)(p + k4 * 64);
            aht[k4] = *(const bf16x8*)(p + 256 + k4 * 64);
        }
    }
    __syncthreads();   // all frags loaded before anyone overwrites h1 span (chunk 24)

    const int par = wave >> 1;   // lattice-row parity of this wave's pairs
    float dsum[4] = {};

    #pragma unroll 1
    for (int c2 = 0; c2 < 32; ++c2) {
        const int j = c2 * 64 + wave * 16 + l15;      // pair index
        const float sb = s_b2[j];
        const float tb = t_b2[j];

        float2 zv[4];
        #pragma unroll
        for (int r = 0; r < 4; ++r)
            zv[r] = zf2[(size_t)(brow + l4 * 4 + r) * 2048 + j];

        f32x4 accS = {}, accT = {};
        #pragma unroll
        for (int k4 = 0; k4 < 4; ++k4) {
            const bf16x8 wsf = *(const bf16x8*)&ws[OFF_SW2T + (size_t)j * 128 + k4 * 32 + l4 * 8];
            const bf16x8 wtf = *(const bf16x8*)&ws[OFF_TW2T + (size_t)j * 128 + k4 * 32 + l4 * 8];
            accS = __builtin_amdgcn_mfma_f32_16x16x32_bf16(ahs[k4], wsf, accS, 0, 0, 0);
            accT = __builtin_amdgcn_mfma_f32_16x16x32_bf16(aht[k4], wtf, accT, 0, 0, 0);
        }

        #pragma unroll
        for (int r = 0; r < 4; ++r) {
            const float sv = accS[r] + sb;
            const float tv = accT[r] + tb;
            const float2 zp = zv[r];
            const float za = par ? zp.y : zp.x;
            const float zb = par ? zp.x : zp.y;
            const float fb = (zb - tv) * __expf(-sv);
            float2 fv;
            if (par) { fv.x = fb; fv.y = za; }
            else     { fv.x = za; fv.y = fb; }
            ff2[(size_t)(brow + l4 * 4 + r) * 2048 + j] = fv;
            dsum[r] += sv;
        }
    }

    // d reduction: over l15 in-wave, then across the 4 waves via tiny LDS
    #pragma unroll
    for (int r = 0; r < 4; ++r) {
        float v = dsum[r];
        v += __shfl_xor(v, 1);
        v += __shfl_xor(v, 2);
        v += __shfl_xor(v, 4);
        v += __shfl_xor(v, 8);
        if (l15 == 0) Dred[wave * 16 + l4 * 4 + r] = v;
    }
    __syncthreads();
    if (tid < 16)
        d_vec[brow + tid] = Dred[tid] + Dred[16 + tid] + Dred[32 + tid] + Dred[48 + tid];
}

extern "C" void kernel_launch(void* const* d_in, const int* in_sizes, int n_in,
                              void* d_out, int out_size, void* d_ws, size_t ws_size,
                              hipStream_t stream) {
    const float* z   = (const float*)d_in[0];
    const float* sW0 = (const float*)d_in[1];
    const float* sW1 = (const float*)d_in[2];
    const float* sW2 = (const float*)d_in[3];
    const float* sb2 = (const float*)d_in[4];
    const float* tW0 = (const float*)d_in[5];
    const float* tW1 = (const float*)d_in[6];
    const float* tW2 = (const float*)d_in[7];
    const float* tb2 = (const float*)d_in[8];

    float* fout = (float*)d_out;
    float* dvec = fout + (size_t)BATCH * 4096;
    unsigned short* ws = (unsigned short*)d_ws;

    hipLaunchKernelGGL(conv_w, dim3(512), dim3(256), 0, stream,
                       sW0, sW1, sW2, tW0, tW1, tW2, ws);
    hipLaunchKernelGGL(layers01, dim3(BATCH / 16), dim3(256), 0, stream,
                       z, ws, (char*)d_out);
    hipLaunchKernelGGL(layer2ep, dim3(BATCH / 16), dim3(256), 0, stream,
                       z, sb2, tb2, ws, fout, dvec);
}

// Round 11
// 294.640 us; speedup vs baseline: 1.1665x; 1.1665x over previous
//
#include <hip/hip_runtime.h>
#include <hip/hip_bf16.h>

#define BATCH  16384
#define SLOPE  0.2f
#define BM     32

typedef __attribute__((ext_vector_type(8))) short bf16x8;
typedef __attribute__((ext_vector_type(4))) float f32x4;
typedef __attribute__((ext_vector_type(4))) float fx4;
typedef __attribute__((ext_vector_type(2))) float fx2;

// ws layout (bf16 element offsets), weights TRANSPOSED as [N][K]; s/t contiguous.
#define OFF_SW0T 0         // [128][2048]
#define OFF_TW0T 262144
#define OFF_SW1T 524288    // [128][128]
#define OFF_TW1T 540672
#define OFF_SW2T 557056    // [2048][128]
#define OFF_TW2T 819200

__device__ __forceinline__ unsigned short f2bf(float f) {
    unsigned int u = __float_as_uint(f);
    u += 0x7FFFu + ((u >> 16) & 1u);   // round-to-nearest-even
    return (unsigned short)(u >> 16);
}

__global__ void conv_w(const float* __restrict__ sW0, const float* __restrict__ sW1,
                       const float* __restrict__ sW2, const float* __restrict__ tW0,
                       const float* __restrict__ tW1, const float* __restrict__ tW2,
                       unsigned short* __restrict__ ws) {
    const int total = 262144 + 16384 + 262144;
    for (int i = blockIdx.x * blockDim.x + threadIdx.x; i < total;
         i += gridDim.x * blockDim.x) {
        if (i < 262144) {                    // W0 [2048][128] -> [128][2048]
            int k = i >> 7, n = i & 127;
            ws[OFF_SW0T + n * 2048 + k] = f2bf(sW0[i]);
            ws[OFF_TW0T + n * 2048 + k] = f2bf(tW0[i]);
        } else if (i < 262144 + 16384) {     // W1 [128][128] -> transpose
            int j = i - 262144;
            int k = j >> 7, n = j & 127;
            ws[OFF_SW1T + n * 128 + k] = f2bf(sW1[j]);
            ws[OFF_TW1T + n * 128 + k] = f2bf(tW1[j]);
        } else {                             // W2 [128][2048] -> [2048][128]
            int j = i - (262144 + 16384);
            int k = j >> 11, n = j & 2047;
            ws[OFF_SW2T + n * 128 + k] = f2bf(sW2[j]);
            ws[OFF_TW2T + n * 128 + k] = f2bf(tW2[j]);
        }
    }
}

// z_a -> bf16, pre-swizzled (octet o stored at position o ^ (b&7)), in the tail
// 4KB of f-row b. Race-free: only row b's own block reads it (layer 0) before
// that block overwrites it (epilogue chunks 24-31). z reads are non-temporal
// so this 256MB stream doesn't evict weights/za from L2.
__global__ void conv_z(const float* __restrict__ z, char* __restrict__ fbytes) {
    const int total = BATCH * 256;
    for (int idx = blockIdx.x * blockDim.x + threadIdx.x; idx < total;
         idx += gridDim.x * blockDim.x) {
        const int b  = idx >> 8;
        const int o  = idx & 255;            // A-octet index (8 A-sites)
        const int rl = o >> 2;               // lattice row (4 octets per row)
        const int par = rl & 1;
        const fx4* src = (const fx4*)(z + (size_t)b * 4096 + rl * 64 + (o & 3) * 16);
        const fx4 v0 = __builtin_nontemporal_load(src + 0);
        const fx4 v1 = __builtin_nontemporal_load(src + 1);
        const fx4 v2 = __builtin_nontemporal_load(src + 2);
        const fx4 v3 = __builtin_nontemporal_load(src + 3);
        union { bf16x8 v; __hip_bfloat162 h[4]; } u;
        u.h[0] = __float22bfloat162_rn(par ? make_float2(v0.y, v0.w) : make_float2(v0.x, v0.z));
        u.h[1] = __float22bfloat162_rn(par ? make_float2(v1.y, v1.w) : make_float2(v1.x, v1.z));
        u.h[2] = __float22bfloat162_rn(par ? make_float2(v2.y, v2.w) : make_float2(v2.x, v2.z));
        u.h[3] = __float22bfloat162_rn(par ? make_float2(v3.y, v3.w) : make_float2(v3.x, v3.z));
        const int oSwz = o ^ (b & 7);
        *(bf16x8*)(fbytes + (size_t)b * 16384 + 12288 + (size_t)oSwz * 16) = u.v;
    }
}

__global__ __launch_bounds__(256, 2) void coupling_main(
    const float* __restrict__ z,
    const float* __restrict__ s_b2,
    const float* __restrict__ t_b2,
    const unsigned short* __restrict__ ws,
    float* __restrict__ f_out,
    float* __restrict__ d_vec) {

    // LDS: [0,16K) Az: 2 granules x 2 chunks x [32 rows][128B]; Dred overlays later
    //      [16K,32K) HA [32][256] u16 swz | [32K,48K) HB
    __shared__ __align__(16) unsigned char LDSbuf[49152];
    unsigned short* HA = (unsigned short*)(LDSbuf + 16384);
    unsigned short* HB = (unsigned short*)(LDSbuf + 32768);
    float* Dred = (float*)LDSbuf;

    const int tid  = threadIdx.x;
    const int wave = tid >> 6;
    const int lane = tid & 63;
    const int l15  = lane & 15;
    const int l4   = lane >> 4;
    const int brow = blockIdx.x * BM;

    const char* fbytes = (const char*)f_out;
    const fx2* __restrict__ zf2 = (const fx2*)z;
    fx2* __restrict__ ff2 = (fx2*)f_out;

    // stage chunk c (64 A-cols = 128B/row, 32 rows) at LDS byte offset `off`
    auto stage = [&](int off, int c) {
        const char* g = fbytes + (size_t)(brow + wave * 8 + (lane >> 3)) * 16384 + 12288
                        + (size_t)(c * 8 + (lane & 7)) * 16;
        void* l = LDSbuf + off + wave * 1024;
        __builtin_amdgcn_global_load_lds(
            (const __attribute__((address_space(1))) unsigned int*)g,
            (__attribute__((address_space(3))) unsigned int*)l, 16, 0, 0);
    };

    // layer-0 weight fragment prefetch (8 frags = one chunk's worth for this wave)
    auto ldw0 = [&](bf16x8 (&w)[8], int c) {
        #pragma unroll
        for (int n2 = 0; n2 < 4; ++n2)
            #pragma unroll
            for (int k2 = 0; k2 < 2; ++k2)
                w[n2 * 2 + k2] = *(const bf16x8*)&ws[OFF_SW0T +
                    (size_t)(wave * 64 + n2 * 16 + l15) * 2048 + c * 64 + k2 * 32 + l4 * 8];
    };

    f32x4 acc0[2][4] = {};   // [m][n2]
    auto cmp0 = [&](const char* Az, bf16x8 (&w)[8]) {
        bf16x8 af[2][2];
        #pragma unroll
        for (int m = 0; m < 2; ++m)
            #pragma unroll
            for (int k2 = 0; k2 < 2; ++k2) {
                const int row = m * 16 + l15;
                af[m][k2] = *(const bf16x8*)(Az + row * 128 +
                              (((k2 * 32 + l4 * 8) * 2) ^ ((row & 7) << 4)));
            }
        #pragma unroll
        for (int n2 = 0; n2 < 4; ++n2)
            #pragma unroll
            for (int k2 = 0; k2 < 2; ++k2)
                #pragma unroll
                for (int m = 0; m < 2; ++m)
                    acc0[m][n2] = __builtin_amdgcn_mfma_f32_16x16x32_bf16(
                        af[m][k2], w[n2 * 2 + k2], acc0[m][n2], 0, 0, 0);
    };

    // ---------------- layer 0: h0 = leaky(z_a @ W0), unified g in [0,256) ----------------
    stage(0, 0);
    stage(4096, 1);
    bf16x8 wA[8], wB[8];
    ldw0(wA, 0);
    __syncthreads();

    #pragma unroll 1
    for (int gIt = 0; gIt < 16; ++gIt) {
        const int cb = (gIt & 1) * 8192;
        if (gIt < 15) {
            const int nb = ((gIt + 1) & 1) * 8192;
            stage(nb, 2 * gIt + 2);
            stage(nb + 4096, 2 * gIt + 3);
        }
        ldw0(wB, 2 * gIt + 1);                         // prefetch half-1 weights
        cmp0((const char*)(LDSbuf + cb), wA);          // compute half 0
        if (gIt < 15) ldw0(wA, 2 * gIt + 2);           // prefetch next half-0
        cmp0((const char*)(LDSbuf + cb + 4096), wB);   // compute half 1
        __syncthreads();
    }

    // leaky relu, h0 -> HA (swizzled)
    #pragma unroll
    for (int m = 0; m < 2; ++m)
        #pragma unroll
        for (int n2 = 0; n2 < 4; ++n2)
            #pragma unroll
            for (int r = 0; r < 4; ++r) {
                float v = acc0[m][n2][r];
                v = v > 0.0f ? v : SLOPE * v;
                const int row = m * 16 + l4 * 4 + r;
                const int col = wave * 64 + n2 * 16 + l15;
                HA[row * 256 + (col ^ ((row & 7) << 3))] = f2bf(v);
            }
    __syncthreads();

    // ---------------- layer 1: h1 = leaky(h0 @ W1) ----------------
    f32x4 acc1[2][4] = {};
    const int net1 = wave >> 1;
    #pragma unroll
    for (int k4 = 0; k4 < 4; ++k4) {
        bf16x8 ahv[2];
        #pragma unroll
        for (int m = 0; m < 2; ++m) {
            const int row = m * 16 + l15;
            ahv[m] = *(const bf16x8*)&HA[row * 256 +
                       ((net1 * 128 + k4 * 32 + l4 * 8) ^ ((row & 7) << 3))];
        }
        #pragma unroll
        for (int n2 = 0; n2 < 4; ++n2) {
            const bf16x8 w = *(const bf16x8*)&ws[OFF_SW1T +
                (size_t)(wave * 64 + n2 * 16 + l15) * 128 + k4 * 32 + l4 * 8];
            #pragma unroll
            for (int m = 0; m < 2; ++m)
                acc1[m][n2] = __builtin_amdgcn_mfma_f32_16x16x32_bf16(
                    ahv[m], w, acc1[m][n2], 0, 0, 0);
        }
    }
    #pragma unroll
    for (int m = 0; m < 2; ++m)
        #pragma unroll
        for (int n2 = 0; n2 < 4; ++n2)
            #pragma unroll
            for (int r = 0; r < 4; ++r) {
                float v = acc1[m][n2][r];
                v = v > 0.0f ? v : SLOPE * v;
                const int row = m * 16 + l4 * 4 + r;
                const int col = wave * 64 + n2 * 16 + l15;
                HB[row * 256 + (col ^ ((row & 7) << 3))] = f2bf(v);
            }
    __syncthreads();

    // ---------------- layer 2 + epilogue: barrier-free, software-pipelined ----------------
    // wave = pair-quarter; pairs in chunk c2: j = c2*64 + wave*16 + l15.
    // Lattice row of j = 2*c2 + (wave>>1) -> parity wave-uniform: par = wave>>1.
    const int par = wave >> 1;

    // hoist A-fragments once
    bf16x8 ahs[2][4], aht[2][4];   // [m][k4]
    #pragma unroll
    for (int m = 0; m < 2; ++m)
        #pragma unroll
        for (int k4 = 0; k4 < 4; ++k4) {
            const int row = m * 16 + l15;
            const int kc = k4 * 32 + l4 * 8;
            ahs[m][k4] = *(const bf16x8*)&HB[row * 256 + (kc ^ ((row & 7) << 3))];
            aht[m][k4] = *(const bf16x8*)&HB[row * 256 + ((128 + kc) ^ ((row & 7) << 3))];
        }

    float dsum[2][4] = {};

    // named pipeline sets (static indexing only — rule #20)
    bf16x8 wS_A[4], wT_A[4], wS_B[4], wT_B[4];
    fx2 zv_A[2][4], zv_B[2][4];
    float sb_A, tb_A, sb_B, tb_B;

    auto ldset = [&](bf16x8 (&wS)[4], bf16x8 (&wT)[4], fx2 (&zv)[2][4],
                     float& sb, float& tb, int c2) {
        const int j = c2 * 64 + wave * 16 + l15;
        sb = s_b2[j];
        tb = t_b2[j];
        #pragma unroll
        for (int k4 = 0; k4 < 4; ++k4) {
            wS[k4] = *(const bf16x8*)&ws[OFF_SW2T + (size_t)j * 128 + k4 * 32 + l4 * 8];
            wT[k4] = *(const bf16x8*)&ws[OFF_TW2T + (size_t)j * 128 + k4 * 32 + l4 * 8];
        }
        #pragma unroll
        for (int m = 0; m < 2; ++m)
            #pragma unroll
            for (int r = 0; r < 4; ++r)
                zv[m][r] = __builtin_nontemporal_load(
                    &zf2[(size_t)(brow + m * 16 + l4 * 4 + r) * 2048 + j]);
    };

    auto body = [&](bf16x8 (&wS)[4], bf16x8 (&wT)[4], fx2 (&zv)[2][4],
                    float sb, float tb, int c2) {
        f32x4 acc2[2][2] = {};   // [net][m]
        #pragma unroll
        for (int k4 = 0; k4 < 4; ++k4)
            #pragma unroll
            for (int m = 0; m < 2; ++m) {
                acc2[0][m] = __builtin_amdgcn_mfma_f32_16x16x32_bf16(
                    ahs[m][k4], wS[k4], acc2[0][m], 0, 0, 0);
                acc2[1][m] = __builtin_amdgcn_mfma_f32_16x16x32_bf16(
                    aht[m][k4], wT[k4], acc2[1][m], 0, 0, 0);
            }
        const int j = c2 * 64 + wave * 16 + l15;
        #pragma unroll
        for (int m = 0; m < 2; ++m)
            #pragma unroll
            for (int r = 0; r < 4; ++r) {
                const float sv = acc2[0][m][r] + sb;
                const float tv = acc2[1][m][r] + tb;
                const fx2 zp = zv[m][r];
                const float za = par ? zp.y : zp.x;
                const float zb = par ? zp.x : zp.y;
                const float fb = (zb - tv) * __expf(-sv);
                fx2 fv;
                if (par) { fv.x = fb; fv.y = za; }
                else     { fv.x = za; fv.y = fb; }
                __builtin_nontemporal_store(fv,
                    &ff2[(size_t)(brow + m * 16 + l4 * 4 + r) * 2048 + j]);
                dsum[m][r] += sv;
            }
    };

    ldset(wS_A, wT_A, zv_A, sb_A, tb_A, 0);
    #pragma unroll 1
    for (int it = 0; it < 16; ++it) {
        ldset(wS_B, wT_B, zv_B, sb_B, tb_B, 2 * it + 1);      // prefetch odd
        body (wS_A, wT_A, zv_A, sb_A, tb_A, 2 * it);
        if (it < 15)
            ldset(wS_A, wT_A, zv_A, sb_A, tb_A, 2 * it + 2);  // prefetch next even
        body (wS_B, wT_B, zv_B, sb_B, tb_B, 2 * it + 1);
    }

    // ---------------- d reduction ----------------
    #pragma unroll
    for (int m = 0; m < 2; ++m)
        #pragma unroll
        for (int r = 0; r < 4; ++r) {
            float v = dsum[m][r];
            v += __shfl_xor(v, 1);
            v += __shfl_xor(v, 2);
            v += __shfl_xor(v, 4);
            v += __shfl_xor(v, 8);
            if (l15 == 0) Dred[wave * 32 + m * 16 + l4 * 4 + r] = v;
        }
    __syncthreads();
    if (tid < BM)
        d_vec[brow + tid] = Dred[tid] + Dred[32 + tid] + Dred[64 + tid] + Dred[96 + tid];
}

extern "C" void kernel_launch(void* const* d_in, const int* in_sizes, int n_in,
                              void* d_out, int out_size, void* d_ws, size_t ws_size,
                              hipStream_t stream) {
    const float* z   = (const float*)d_in[0];
    const float* sW0 = (const float*)d_in[1];
    const float* sW1 = (const float*)d_in[2];
    const float* sW2 = (const float*)d_in[3];
    const float* sb2 = (const float*)d_in[4];
    const float* tW0 = (const float*)d_in[5];
    const float* tW1 = (const float*)d_in[6];
    const float* tW2 = (const float*)d_in[7];
    const float* tb2 = (const float*)d_in[8];

    float* fout = (float*)d_out;
    float* dvec = fout + (size_t)BATCH * 4096;
    unsigned short* ws = (unsigned short*)d_ws;

    hipLaunchKernelGGL(conv_w, dim3(512), dim3(256), 0, stream,
                       sW0, sW1, sW2, tW0, tW1, tW2, ws);
    hipLaunchKernelGGL(conv_z, dim3(4096), dim3(256), 0, stream,
                       z, (char*)d_out);
    hipLaunchKernelGGL(coupling_main, dim3(BATCH / BM), dim3(256), 0, stream,
                       z, sb2, tb2, ws, fout, dvec);
}

// Round 12
// 235.483 us; speedup vs baseline: 1.4596x; 1.2512x over previous
//
#include <hip/hip_runtime.h>
#include <hip/hip_bf16.h>

#define BATCH  16384
#define SLOPE  0.2f
#define BM     32

typedef __attribute__((ext_vector_type(8))) short bf16x8;
typedef __attribute__((ext_vector_type(4))) float f32x4;
typedef __attribute__((ext_vector_type(4))) float fx4;
typedef __attribute__((ext_vector_type(2))) float fx2;

// ws layout (bf16 element offsets), weights TRANSPOSED as [N][K]; s/t contiguous.
// W0T and W2T rows are PRE-SWIZZLED: 16B unit v of row n stored at v ^ (n&7)
// (within each 128B chunk for W0T; within the whole 256B row for W2T).
#define OFF_SW0T 0         // [128][2048]
#define OFF_TW0T 262144
#define OFF_SW1T 524288    // [128][128] (unswizzled)
#define OFF_TW1T 540672
#define OFF_SW2T 557056    // [2048][128]
#define OFF_TW2T 819200

__device__ __forceinline__ unsigned short f2bf(float f) {
    unsigned int u = __float_as_uint(f);
    u += 0x7FFFu + ((u >> 16) & 1u);   // round-to-nearest-even
    return (unsigned short)(u >> 16);
}

__global__ void conv_w(const float* __restrict__ sW0, const float* __restrict__ sW1,
                       const float* __restrict__ sW2, const float* __restrict__ tW0,
                       const float* __restrict__ tW1, const float* __restrict__ tW2,
                       unsigned short* __restrict__ ws) {
    const int total = 262144 + 16384 + 262144;
    for (int i = blockIdx.x * blockDim.x + threadIdx.x; i < total;
         i += gridDim.x * blockDim.x) {
        if (i < 262144) {                    // W0 [2048][128] -> [128][2048], swz
            int k = i >> 7, n = i & 127;
            int ks = (k & ~63) | ((((k >> 3) & 7) ^ (n & 7)) << 3) | (k & 7);
            ws[OFF_SW0T + n * 2048 + ks] = f2bf(sW0[i]);
            ws[OFF_TW0T + n * 2048 + ks] = f2bf(tW0[i]);
        } else if (i < 262144 + 16384) {     // W1 [128][128] -> transpose (no swz)
            int j = i - 262144;
            int k = j >> 7, n = j & 127;
            ws[OFF_SW1T + n * 128 + k] = f2bf(sW1[j]);
            ws[OFF_TW1T + n * 128 + k] = f2bf(tW1[j]);
        } else {                             // W2 [128][2048] -> [2048][128], swz
            int j = i - (262144 + 16384);
            int k = j >> 11, n = j & 2047;
            int ks = ((((k >> 3) & 15) ^ (n & 7)) << 3) | (k & 7);
            ws[OFF_SW2T + n * 128 + ks] = f2bf(sW2[j]);
            ws[OFF_TW2T + n * 128 + ks] = f2bf(tW2[j]);
        }
    }
}

// z_a -> bf16, pre-swizzled (octet o stored at o ^ (b&7)), in the tail 4KB of
// f-row b. Race-free: only row b's own block reads it (L0) before that block
// overwrites it (epilogue chunk 24).
__global__ void conv_z(const float* __restrict__ z, char* __restrict__ fbytes) {
    const int total = BATCH * 256;
    for (int idx = blockIdx.x * blockDim.x + threadIdx.x; idx < total;
         idx += gridDim.x * blockDim.x) {
        const int b  = idx >> 8;
        const int o  = idx & 255;            // A-octet index (8 A-sites)
        const int rl = o >> 2;               // lattice row (4 octets per row)
        const int par = rl & 1;
        const fx4* src = (const fx4*)(z + (size_t)b * 4096 + rl * 64 + (o & 3) * 16);
        const fx4 v0 = __builtin_nontemporal_load(src + 0);
        const fx4 v1 = __builtin_nontemporal_load(src + 1);
        const fx4 v2 = __builtin_nontemporal_load(src + 2);
        const fx4 v3 = __builtin_nontemporal_load(src + 3);
        union { bf16x8 v; __hip_bfloat162 h[4]; } u;
        u.h[0] = __float22bfloat162_rn(par ? make_float2(v0.y, v0.w) : make_float2(v0.x, v0.z));
        u.h[1] = __float22bfloat162_rn(par ? make_float2(v1.y, v1.w) : make_float2(v1.x, v1.z));
        u.h[2] = __float22bfloat162_rn(par ? make_float2(v2.y, v2.w) : make_float2(v2.x, v2.z));
        u.h[3] = __float22bfloat162_rn(par ? make_float2(v3.y, v3.w) : make_float2(v3.x, v3.z));
        const int oSwz = o ^ (b & 7);
        *(bf16x8*)(fbytes + (size_t)b * 16384 + 12288 + (size_t)oSwz * 16) = u.v;
    }
}

__global__ __launch_bounds__(256, 2) void coupling_main(
    const float* __restrict__ z,
    const float* __restrict__ s_b2,
    const float* __restrict__ t_b2,
    const unsigned short* __restrict__ ws,
    float* __restrict__ f_out,
    float* __restrict__ d_vec) {

    // LDS map: L0: [0,8K) Az dbuf (2x4K) | [8K,72K) W0 tile dbuf (2x32K)
    //          L1: HA [0,16K) | HB [16K,32K)   (L0 regions dead)
    //          L2: W2 tile [32K,64K) | Dred [0,512)
    __shared__ __align__(16) unsigned char LDSbuf[73728];
    unsigned short* HA = (unsigned short*)(LDSbuf);
    unsigned short* HB = (unsigned short*)(LDSbuf + 16384);
    float* Dred = (float*)LDSbuf;

    const int tid  = threadIdx.x;
    const int wave = tid >> 6;
    const int lane = tid & 63;
    const int l15  = lane & 15;
    const int l4   = lane >> 4;
    const int brow = blockIdx.x * BM;

    const char* fbytes = (const char*)f_out;
    const char* wsb = (const char*)ws;
    const fx2* __restrict__ zf2 = (const fx2*)z;
    fx2* __restrict__ ff2 = (fx2*)f_out;

    // ---- staging helpers ----
    auto stageAz = [&](int b, int c) {   // 32 rows x 128B (chunk c of za)
        const char* g = fbytes + (size_t)(brow + wave * 8 + (lane >> 3)) * 16384 + 12288
                        + (size_t)(c * 8 + (lane & 7)) * 16;
        void* l = LDSbuf + b * 4096 + wave * 1024;
        __builtin_amdgcn_global_load_lds(
            (const __attribute__((address_space(1))) unsigned int*)g,
            (__attribute__((address_space(3))) unsigned int*)l, 16, 0, 0);
    };
    auto stageW0 = [&](int b, int c) {   // 256 g-rows x 128B (K-chunk c), pre-swz src
        #pragma unroll
        for (int jj = 0; jj < 8; ++jj) {
            const char* g = wsb + (size_t)(wave * 64 + jj * 8 + (lane >> 3)) * 4096
                            + c * 128 + (lane & 7) * 16;
            void* l = LDSbuf + 8192 + b * 32768 + (wave * 64 + jj * 8) * 128;
            __builtin_amdgcn_global_load_lds(
                (const __attribute__((address_space(1))) unsigned int*)g,
                (__attribute__((address_space(3))) unsigned int*)l, 16, 0, 0);
        }
    };

    // ---------------- layer 0: h0 = leaky(z_a @ W0), both ops LDS-staged ----------------
    stageAz(0, 0);
    stageW0(0, 0);
    __syncthreads();

    f32x4 acc0[2][4] = {};   // [m][n2]
    #pragma unroll 1
    for (int c = 0; c < 32; ++c) {
        const int cb = c & 1, nb = cb ^ 1;
        if (c < 31) { stageAz(nb, c + 1); stageW0(nb, c + 1); }
        const char* Az = (const char*)(LDSbuf + cb * 4096);
        const char* Wt = (const char*)(LDSbuf + 8192 + cb * 32768);
        bf16x8 af[2][2], wf[4][2];
        #pragma unroll
        for (int m = 0; m < 2; ++m)
            #pragma unroll
            for (int k2 = 0; k2 < 2; ++k2) {
                const int row = m * 16 + l15;
                af[m][k2] = *(const bf16x8*)(Az + row * 128 +
                              (((k2 * 32 + l4 * 8) * 2) ^ ((row & 7) << 4)));
            }
        #pragma unroll
        for (int n2 = 0; n2 < 4; ++n2)
            #pragma unroll
            for (int k2 = 0; k2 < 2; ++k2) {
                const int g = wave * 64 + n2 * 16 + l15;
                wf[n2][k2] = *(const bf16x8*)(Wt + g * 128 +
                               ((k2 * 64 + l4 * 16) ^ ((g & 7) << 4)));
            }
        #pragma unroll
        for (int n2 = 0; n2 < 4; ++n2)
            #pragma unroll
            for (int k2 = 0; k2 < 2; ++k2)
                #pragma unroll
                for (int m = 0; m < 2; ++m)
                    acc0[m][n2] = __builtin_amdgcn_mfma_f32_16x16x32_bf16(
                        af[m][k2], wf[n2][k2], acc0[m][n2], 0, 0, 0);
        __syncthreads();
    }

    // leaky, h0 -> HA (swizzled [32][256])
    #pragma unroll
    for (int m = 0; m < 2; ++m)
        #pragma unroll
        for (int n2 = 0; n2 < 4; ++n2)
            #pragma unroll
            for (int r = 0; r < 4; ++r) {
                float v = acc0[m][n2][r];
                v = v > 0.0f ? v : SLOPE * v;
                const int row = m * 16 + l4 * 4 + r;
                const int col = wave * 64 + n2 * 16 + l15;
                HA[row * 256 + (col ^ ((row & 7) << 3))] = f2bf(v);
            }
    __syncthreads();

    // ---------------- layer 1: h1 = leaky(h0 @ W1) (direct global W1T) ----------------
    f32x4 acc1[2][4] = {};
    const int net1 = wave >> 1;
    #pragma unroll
    for (int k4 = 0; k4 < 4; ++k4) {
        bf16x8 ahv[2];
        #pragma unroll
        for (int m = 0; m < 2; ++m) {
            const int row = m * 16 + l15;
            ahv[m] = *(const bf16x8*)&HA[row * 256 +
                       ((net1 * 128 + k4 * 32 + l4 * 8) ^ ((row & 7) << 3))];
        }
        #pragma unroll
        for (int n2 = 0; n2 < 4; ++n2) {
            const bf16x8 w = *(const bf16x8*)&ws[OFF_SW1T +
                (size_t)(wave * 64 + n2 * 16 + l15) * 128 + k4 * 32 + l4 * 8];
            #pragma unroll
            for (int m = 0; m < 2; ++m)
                acc1[m][n2] = __builtin_amdgcn_mfma_f32_16x16x32_bf16(
                    ahv[m], w, acc1[m][n2], 0, 0, 0);
        }
    }
    __syncthreads();   // HA reads done
    #pragma unroll
    for (int m = 0; m < 2; ++m)
        #pragma unroll
        for (int n2 = 0; n2 < 4; ++n2)
            #pragma unroll
            for (int r = 0; r < 4; ++r) {
                float v = acc1[m][n2][r];
                v = v > 0.0f ? v : SLOPE * v;
                const int row = m * 16 + l4 * 4 + r;
                const int col = wave * 64 + n2 * 16 + l15;
                HB[row * 256 + (col ^ ((row & 7) << 3))] = f2bf(v);
            }
    __syncthreads();

    // ---------------- layer 2 + epilogue: W2 tile LDS-staged ----------------
    const int par = wave >> 1;   // lattice-row parity of this wave's pairs

    // hoist A-fragments once (both nets)
    bf16x8 ahs[2][4], aht[2][4];   // [m][k4]
    #pragma unroll
    for (int m = 0; m < 2; ++m)
        #pragma unroll
        for (int k4 = 0; k4 < 4; ++k4) {
            const int row = m * 16 + l15;
            const int kc = k4 * 32 + l4 * 8;
            ahs[m][k4] = *(const bf16x8*)&HB[row * 256 + (kc ^ ((row & 7) << 3))];
            aht[m][k4] = *(const bf16x8*)&HB[row * 256 + ((128 + kc) ^ ((row & 7) << 3))];
        }
    __syncthreads();

    float dsum[2][4] = {};
    #pragma unroll 1
    for (int c2 = 0; c2 < 32; ++c2) {
        // stage W2 tile: 128 rows (net*64 + local-pair) x 256B, pre-swz src
        #pragma unroll
        for (int jj = 0; jj < 8; ++jj) {
            const int r  = wave * 32 + jj * 4 + (lane >> 4);
            const int pr = c2 * 64 + (r & 63);
            const char* g = wsb + (size_t)((r >> 6) ? OFF_TW2T : OFF_SW2T) * 2
                            + (size_t)pr * 256 + (lane & 15) * 16;
            void* l = LDSbuf + 32768 + (wave * 32 + jj * 4) * 256;
            __builtin_amdgcn_global_load_lds(
                (const __attribute__((address_space(1))) unsigned int*)g,
                (__attribute__((address_space(3))) unsigned int*)l, 16, 0, 0);
        }
        __syncthreads();   // drain stage

        const int j = c2 * 64 + wave * 16 + l15;      // global pair index
        const float sb = s_b2[j];
        const float tb = t_b2[j];
        fx2 zv[2][4];
        #pragma unroll
        for (int m = 0; m < 2; ++m)
            #pragma unroll
            for (int r = 0; r < 4; ++r)
                zv[m][r] = __builtin_nontemporal_load(
                    &zf2[(size_t)(brow + m * 16 + l4 * 4 + r) * 2048 + j]);

        bf16x8 wfs[4], wft[4];
        #pragma unroll
        for (int k4 = 0; k4 < 4; ++k4) {
            const int rs = wave * 16 + l15;
            const int rt = 64 + wave * 16 + l15;
            const int kc = k4 * 64 + l4 * 16;
            wfs[k4] = *(const bf16x8*)(LDSbuf + 32768 + rs * 256 + (kc ^ ((rs & 7) << 4)));
            wft[k4] = *(const bf16x8*)(LDSbuf + 32768 + rt * 256 + (kc ^ ((rt & 7) << 4)));
        }

        f32x4 acc2[2][2] = {};   // [net][m]
        #pragma unroll
        for (int k4 = 0; k4 < 4; ++k4)
            #pragma unroll
            for (int m = 0; m < 2; ++m) {
                acc2[0][m] = __builtin_amdgcn_mfma_f32_16x16x32_bf16(
                    ahs[m][k4], wfs[k4], acc2[0][m], 0, 0, 0);
                acc2[1][m] = __builtin_amdgcn_mfma_f32_16x16x32_bf16(
                    aht[m][k4], wft[k4], acc2[1][m], 0, 0, 0);
            }

        #pragma unroll
        for (int m = 0; m < 2; ++m)
            #pragma unroll
            for (int r = 0; r < 4; ++r) {
                const float sv = acc2[0][m][r] + sb;
                const float tv = acc2[1][m][r] + tb;
                const fx2 zp = zv[m][r];
                const float za = par ? zp.y : zp.x;
                const float zb = par ? zp.x : zp.y;
                const float fb = (zb - tv) * __expf(-sv);
                fx2 fv;
                if (par) { fv.x = fb; fv.y = za; }
                else     { fv.x = za; fv.y = fb; }
                __builtin_nontemporal_store(fv,
                    &ff2[(size_t)(brow + m * 16 + l4 * 4 + r) * 2048 + j]);
                dsum[m][r] += sv;
            }
        __syncthreads();   // protect tile for next stage
    }

    // ---------------- d reduction ----------------
    #pragma unroll
    for (int m = 0; m < 2; ++m)
        #pragma unroll
        for (int r = 0; r < 4; ++r) {
            float v = dsum[m][r];
            v += __shfl_xor(v, 1);
            v += __shfl_xor(v, 2);
            v += __shfl_xor(v, 4);
            v += __shfl_xor(v, 8);
            if (l15 == 0) Dred[wave * 32 + m * 16 + l4 * 4 + r] = v;
        }
    __syncthreads();
    if (tid < BM)
        d_vec[brow + tid] = Dred[tid] + Dred[32 + tid] + Dred[64 + tid] + Dred[96 + tid];
}

extern "C" void kernel_launch(void* const* d_in, const int* in_sizes, int n_in,
                              void* d_out, int out_size, void* d_ws, size_t ws_size,
                              hipStream_t stream) {
    const float* z   = (const float*)d_in[0];
    const float* sW0 = (const float*)d_in[1];
    const float* sW1 = (const float*)d_in[2];
    const float* sW2 = (const float*)d_in[3];
    const float* sb2 = (const float*)d_in[4];
    const float* tW0 = (const float*)d_in[5];
    const float* tW1 = (const float*)d_in[6];
    const float* tW2 = (const float*)d_in[7];
    const float* tb2 = (const float*)d_in[8];

    float* fout = (float*)d_out;
    float* dvec = fout + (size_t)BATCH * 4096;
    unsigned short* ws = (unsigned short*)d_ws;

    hipLaunchKernelGGL(conv_w, dim3(512), dim3(256), 0, stream,
                       sW0, sW1, sW2, tW0, tW1, tW2, ws);
    hipLaunchKernelGGL(conv_z, dim3(4096), dim3(256), 0, stream,
                       z, (char*)d_out);
    hipLaunchKernelGGL(coupling_main, dim3(BATCH / BM), dim3(256), 0, stream,
                       z, sb2, tb2, ws, fout, dvec);
}

// Round 13
// 183.465 us; speedup vs baseline: 1.8734x; 1.2835x over previous
//
#include <hip/hip_runtime.h>
#include <hip/hip_bf16.h>

#define BATCH  16384
#define SLOPE  0.2f
#define BM     32

typedef __attribute__((ext_vector_type(8))) short bf16x8;
typedef __attribute__((ext_vector_type(4))) float f32x4;
typedef __attribute__((ext_vector_type(4))) float fx4;
typedef __attribute__((ext_vector_type(2))) float fx2;

// ws layout (bf16 element offsets), weights TRANSPOSED as [N][K]; s/t contiguous.
// W0T and W2T rows are PRE-SWIZZLED in 16B units: unit u of row n at u ^ (n&7)
// (within each 128B chunk for W0T; within the 256B row for W2T).
#define OFF_SW0T 0         // [128][2048]
#define OFF_TW0T 262144
#define OFF_SW1T 524288    // [128][128] (unswizzled)
#define OFF_TW1T 540672
#define OFF_SW2T 557056    // [2048][128]
#define OFF_TW2T 819200

__device__ __forceinline__ unsigned short f2bf(float f) {
    unsigned int u = __float_as_uint(f);
    u += 0x7FFFu + ((u >> 16) & 1u);   // round-to-nearest-even
    return (unsigned short)(u >> 16);
}

__global__ void conv_w(const float* __restrict__ sW0, const float* __restrict__ sW1,
                       const float* __restrict__ sW2, const float* __restrict__ tW0,
                       const float* __restrict__ tW1, const float* __restrict__ tW2,
                       unsigned short* __restrict__ ws) {
    const int total = 262144 + 16384 + 262144;
    for (int i = blockIdx.x * blockDim.x + threadIdx.x; i < total;
         i += gridDim.x * blockDim.x) {
        if (i < 262144) {                    // W0 [2048][128] -> [128][2048], swz
            int k = i >> 7, n = i & 127;
            int ks = (k & ~63) | ((((k >> 3) & 7) ^ (n & 7)) << 3) | (k & 7);
            ws[OFF_SW0T + n * 2048 + ks] = f2bf(sW0[i]);
            ws[OFF_TW0T + n * 2048 + ks] = f2bf(tW0[i]);
        } else if (i < 262144 + 16384) {     // W1 [128][128] -> transpose (no swz)
            int j = i - 262144;
            int k = j >> 7, n = j & 127;
            ws[OFF_SW1T + n * 128 + k] = f2bf(sW1[j]);
            ws[OFF_TW1T + n * 128 + k] = f2bf(tW1[j]);
        } else {                             // W2 [128][2048] -> [2048][128], swz
            int j = i - (262144 + 16384);
            int k = j >> 11, n = j & 2047;
            int ks = ((((k >> 3) & 15) ^ (n & 7)) << 3) | (k & 7);
            ws[OFF_SW2T + n * 128 + ks] = f2bf(sW2[j]);
            ws[OFF_TW2T + n * 128 + ks] = f2bf(tW2[j]);
        }
    }
}

__global__ __launch_bounds__(256, 2) void coupling_main(
    const float* __restrict__ z,
    const float* __restrict__ s_b2,
    const float* __restrict__ t_b2,
    const unsigned short* __restrict__ ws,
    float* __restrict__ f_out,
    float* __restrict__ d_vec) {

    // LDS map:
    //   L0: Az dbuf [0,8K) (2x4K) | W0 dbuf [8K,72K) (2x32K)
    //   L1: HA [8K,24K) | HB [24K,40K)      (L0 regions dead)
    //   L2: W2 dbuf [0,64K) | Dred [64K,64K+512)
    __shared__ __align__(16) unsigned char LDSbuf[73728];
    unsigned short* HA = (unsigned short*)(LDSbuf + 8192);
    unsigned short* HB = (unsigned short*)(LDSbuf + 24576);
    float* Dred = (float*)(LDSbuf + 65536);

    const int tid  = threadIdx.x;
    const int wave = tid >> 6;
    const int lane = tid & 63;
    const int l15  = lane & 15;
    const int l4   = lane >> 4;
    const int brow = blockIdx.x * BM;

    const char* wsb = (const char*)ws;
    const fx4* __restrict__ zf4 = (const fx4*)z;
    const fx2* __restrict__ zf2 = (const fx2*)z;
    fx2* __restrict__ ff2 = (fx2*)f_out;

    // ---- L0 staging helpers ----
    // z chunk c covers z-cols [c*128,(c+1)*128) of 32 rows = 1024 fx4 / block.
    // fx4 index f = tid + 256q: row = f>>5, col16 = f&31.
    auto ldzTo = [&](fx4 (&zr)[4], int c) {
        #pragma unroll
        for (int q = 0; q < 4; ++q) {
            const int f = tid + 256 * q;
            const int row = f >> 5, col16 = f & 31;
            zr[q] = __builtin_nontemporal_load(
                zf4 + (size_t)(brow + row) * 1024 + c * 32 + col16);
        }
    };
    // extract A-sites (parity = lattice-row parity = col16>>4), pack 2xbf16,
    // swizzled ds_write into Az buffer b.
    auto wrzFrom = [&](fx4 (&zr)[4], int b) {
        #pragma unroll
        for (int q = 0; q < 4; ++q) {
            const int f = tid + 256 * q;
            const int row = f >> 5, col16 = f & 31;
            const int par = (col16 >> 4) & 1;
            const float a0 = par ? zr[q].y : zr[q].x;
            const float a1 = par ? zr[q].w : zr[q].z;
            const unsigned int pk = (unsigned int)f2bf(a0) | ((unsigned int)f2bf(a1) << 16);
            *(unsigned int*)(LDSbuf + b * 4096 + row * 128 +
                             (((col16 >> 2) ^ (row & 7)) << 4) + (col16 & 3) * 4) = pk;
        }
    };
    auto stageW0 = [&](int b, int c) {   // 256 g-rows x 128B (K-chunk c), pre-swz src
        #pragma unroll
        for (int jj = 0; jj < 8; ++jj) {
            const char* g = wsb + (size_t)(wave * 64 + jj * 8 + (lane >> 3)) * 4096
                            + c * 128 + (lane & 7) * 16;
            void* l = LDSbuf + 8192 + b * 32768 + (wave * 64 + jj * 8) * 128;
            __builtin_amdgcn_global_load_lds(
                (const __attribute__((address_space(1))) unsigned int*)g,
                (__attribute__((address_space(3))) unsigned int*)l, 16, 0, 0);
        }
    };

    f32x4 acc0[2][4] = {};   // [m][n2]
    auto cmp0 = [&](int cb) {
        const char* Az = (const char*)(LDSbuf + cb * 4096);
        const char* Wt = (const char*)(LDSbuf + 8192 + cb * 32768);
        bf16x8 af[2][2], wf[4][2];
        #pragma unroll
        for (int m = 0; m < 2; ++m)
            #pragma unroll
            for (int k2 = 0; k2 < 2; ++k2) {
                const int row = m * 16 + l15;
                af[m][k2] = *(const bf16x8*)(Az + row * 128 +
                              ((k2 * 64 + l4 * 16) ^ ((row & 7) << 4)));
            }
        #pragma unroll
        for (int n2 = 0; n2 < 4; ++n2)
            #pragma unroll
            for (int k2 = 0; k2 < 2; ++k2) {
                const int g = wave * 64 + n2 * 16 + l15;
                wf[n2][k2] = *(const bf16x8*)(Wt + g * 128 +
                               ((k2 * 64 + l4 * 16) ^ ((g & 7) << 4)));
            }
        #pragma unroll
        for (int n2 = 0; n2 < 4; ++n2)
            #pragma unroll
            for (int k2 = 0; k2 < 2; ++k2)
                #pragma unroll
                for (int m = 0; m < 2; ++m)
                    acc0[m][n2] = __builtin_amdgcn_mfma_f32_16x16x32_bf16(
                        af[m][k2], wf[n2][k2], acc0[m][n2], 0, 0, 0);
    };

    fx4 zA[4], zB[4];
    // phase p: compute tile p (bufs p&1); stage W0 p+1; issue z p+2 into zLd;
    // write z p+1 (zWr) into other Az buf; counted wait leaves only this
    // phase's 4 z loads in flight across the raw barrier.
    auto phase = [&](int p, int cb, fx4 (&zLd)[4], fx4 (&zWr)[4]) {
        if (p + 1 < 32) stageW0(cb ^ 1, p + 1);
        if (p + 2 < 32) ldzTo(zLd, p + 2);
        cmp0(cb);
        if (p + 1 < 32) wrzFrom(zWr, cb ^ 1);
        if (p + 2 < 32)
            asm volatile("s_waitcnt lgkmcnt(0) vmcnt(4)" ::: "memory");
        else
            asm volatile("s_waitcnt lgkmcnt(0) vmcnt(0)" ::: "memory");
        __builtin_amdgcn_s_barrier();
        __builtin_amdgcn_sched_barrier(0);
    };

    // ---------------- layer 0: h0 = leaky(z_a @ W0), unified g in [0,256) ----------------
    ldzTo(zB, 0);
    stageW0(0, 0);
    wrzFrom(zB, 0);          // Az0 <- tile 0 (auto vmcnt for zB)
    ldzTo(zB, 1);            // zB <- tile 1
    asm volatile("s_waitcnt lgkmcnt(0) vmcnt(4)" ::: "memory");
    __builtin_amdgcn_s_barrier();
    __builtin_amdgcn_sched_barrier(0);

    #pragma unroll 1
    for (int gIt = 0; gIt < 16; ++gIt) {
        phase(2 * gIt,     0, zA, zB);
        phase(2 * gIt + 1, 1, zB, zA);
    }

    // leaky, h0 -> HA (swizzled [32][256])
    #pragma unroll
    for (int m = 0; m < 2; ++m)
        #pragma unroll
        for (int n2 = 0; n2 < 4; ++n2)
            #pragma unroll
            for (int r = 0; r < 4; ++r) {
                float v = acc0[m][n2][r];
                v = v > 0.0f ? v : SLOPE * v;
                const int row = m * 16 + l4 * 4 + r;
                const int col = wave * 64 + n2 * 16 + l15;
                HA[row * 256 + (col ^ ((row & 7) << 3))] = f2bf(v);
            }
    __syncthreads();

    // ---------------- layer 1: h1 = leaky(h0 @ W1) (direct global W1T) ----------------
    f32x4 acc1[2][4] = {};
    const int net1 = wave >> 1;
    #pragma unroll
    for (int k4 = 0; k4 < 4; ++k4) {
        bf16x8 ahv[2];
        #pragma unroll
        for (int m = 0; m < 2; ++m) {
            const int row = m * 16 + l15;
            ahv[m] = *(const bf16x8*)&HA[row * 256 +
                       ((net1 * 128 + k4 * 32 + l4 * 8) ^ ((row & 7) << 3))];
        }
        #pragma unroll
        for (int n2 = 0; n2 < 4; ++n2) {
            const bf16x8 w = *(const bf16x8*)&ws[OFF_SW1T +
                (size_t)(wave * 64 + n2 * 16 + l15) * 128 + k4 * 32 + l4 * 8];
            #pragma unroll
            for (int m = 0; m < 2; ++m)
                acc1[m][n2] = __builtin_amdgcn_mfma_f32_16x16x32_bf16(
                    ahv[m], w, acc1[m][n2], 0, 0, 0);
        }
    }
    __syncthreads();   // HA reads done
    #pragma unroll
    for (int m = 0; m < 2; ++m)
        #pragma unroll
        for (int n2 = 0; n2 < 4; ++n2)
            #pragma unroll
            for (int r = 0; r < 4; ++r) {
                float v = acc1[m][n2][r];
                v = v > 0.0f ? v : SLOPE * v;
                const int row = m * 16 + l4 * 4 + r;
                const int col = wave * 64 + n2 * 16 + l15;
                HB[row * 256 + (col ^ ((row & 7) << 3))] = f2bf(v);
            }
    __syncthreads();

    // ---------------- layer 2 + epilogue: W2 tile double-buffered ----------------
    const int par = wave >> 1;   // lattice-row parity of this wave's pairs

    // hoist A-fragments once (both nets)
    bf16x8 ahs[2][4], aht[2][4];   // [m][k4]
    #pragma unroll
    for (int m = 0; m < 2; ++m)
        #pragma unroll
        for (int k4 = 0; k4 < 4; ++k4) {
            const int row = m * 16 + l15;
            const int kc = k4 * 32 + l4 * 8;
            ahs[m][k4] = *(const bf16x8*)&HB[row * 256 + (kc ^ ((row & 7) << 3))];
            aht[m][k4] = *(const bf16x8*)&HB[row * 256 + ((128 + kc) ^ ((row & 7) << 3))];
        }
    __syncthreads();   // HB region overlaps W2 buf0 — all reads done first

    auto stageW2 = [&](int b, int c2) {  // 128 rows (net*64+pair) x 256B, pre-swz src
        #pragma unroll
        for (int jj = 0; jj < 8; ++jj) {
            const int r  = wave * 32 + jj * 4 + (lane >> 4);
            const int pr = c2 * 64 + (r & 63);
            const char* g = wsb + (size_t)((r >> 6) ? OFF_TW2T : OFF_SW2T) * 2
                            + (size_t)pr * 256 + (lane & 15) * 16;
            void* l = LDSbuf + b * 32768 + (wave * 32 + jj * 4) * 256;
            __builtin_amdgcn_global_load_lds(
                (const __attribute__((address_space(1))) unsigned int*)g,
                (__attribute__((address_space(3))) unsigned int*)l, 16, 0, 0);
        }
    };

    stageW2(0, 0);
    __syncthreads();   // drain

    float dsum[2][4] = {};
    #pragma unroll 1
    for (int c2 = 0; c2 < 32; ++c2) {
        const int cb = c2 & 1;
        if (c2 < 31) stageW2(cb ^ 1, c2 + 1);

        const int j = c2 * 64 + wave * 16 + l15;      // global pair index
        const float sb = s_b2[j];
        const float tb = t_b2[j];
        fx2 zv[2][4];
        #pragma unroll
        for (int m = 0; m < 2; ++m)
            #pragma unroll
            for (int r = 0; r < 4; ++r)
                zv[m][r] = __builtin_nontemporal_load(
                    &zf2[(size_t)(brow + m * 16 + l4 * 4 + r) * 2048 + j]);

        bf16x8 wfs[4], wft[4];
        #pragma unroll
        for (int k4 = 0; k4 < 4; ++k4) {
            const int rs = wave * 16 + l15;
            const int rt = 64 + wave * 16 + l15;
            const int kc = k4 * 64 + l4 * 16;
            wfs[k4] = *(const bf16x8*)(LDSbuf + cb * 32768 + rs * 256 + (kc ^ ((rs & 7) << 4)));
            wft[k4] = *(const bf16x8*)(LDSbuf + cb * 32768 + rt * 256 + (kc ^ ((rt & 7) << 4)));
        }

        f32x4 acc2[2][2] = {};   // [net][m]
        #pragma unroll
        for (int k4 = 0; k4 < 4; ++k4)
            #pragma unroll
            for (int m = 0; m < 2; ++m) {
                acc2[0][m] = __builtin_amdgcn_mfma_f32_16x16x32_bf16(
                    ahs[m][k4], wfs[k4], acc2[0][m], 0, 0, 0);
                acc2[1][m] = __builtin_amdgcn_mfma_f32_16x16x32_bf16(
                    aht[m][k4], wft[k4], acc2[1][m], 0, 0, 0);
            }

        #pragma unroll
        for (int m = 0; m < 2; ++m)
            #pragma unroll
            for (int r = 0; r < 4; ++r) {
                const float sv = acc2[0][m][r] + sb;
                const float tv = acc2[1][m][r] + tb;
                const fx2 zp = zv[m][r];
                const float za = par ? zp.y : zp.x;
                const float zb = par ? zp.x : zp.y;
                const float fb = (zb - tv) * __expf(-sv);
                fx2 fv;
                if (par) { fv.x = fb; fv.y = za; }
                else     { fv.x = za; fv.y = fb; }
                __builtin_nontemporal_store(fv,
                    &ff2[(size_t)(brow + m * 16 + l4 * 4 + r) * 2048 + j]);
                dsum[m][r] += sv;
            }
        __syncthreads();   // next tile staged & visible
    }

    // ---------------- d reduction ----------------
    #pragma unroll
    for (int m = 0; m < 2; ++m)
        #pragma unroll
        for (int r = 0; r < 4; ++r) {
            float v = dsum[m][r];
            v += __shfl_xor(v, 1);
            v += __shfl_xor(v, 2);
            v += __shfl_xor(v, 4);
            v += __shfl_xor(v, 8);
            if (l15 == 0) Dred[wave * 32 + m * 16 + l4 * 4 + r] = v;
        }
    __syncthreads();
    if (tid < BM)
        d_vec[brow + tid] = Dred[tid] + Dred[32 + tid] + Dred[64 + tid] + Dred[96 + tid];
}

extern "C" void kernel_launch(void* const* d_in, const int* in_sizes, int n_in,
                              void* d_out, int out_size, void* d_ws, size_t ws_size,
                              hipStream_t stream) {
    const float* z   = (const float*)d_in[0];
    const float* sW0 = (const float*)d_in[1];
    const float* sW1 = (const float*)d_in[2];
    const float* sW2 = (const float*)d_in[3];
    const float* sb2 = (const float*)d_in[4];
    const float* tW0 = (const float*)d_in[5];
    const float* tW1 = (const float*)d_in[6];
    const float* tW2 = (const float*)d_in[7];
    const float* tb2 = (const float*)d_in[8];

    float* fout = (float*)d_out;
    float* dvec = fout + (size_t)BATCH * 4096;
    unsigned short* ws = (unsigned short*)d_ws;

    hipLaunchKernelGGL(conv_w, dim3(512), dim3(256), 0, stream,
                       sW0, sW1, sW2, tW0, tW1, tW2, ws);
    hipLaunchKernelGGL(coupling_main, dim3(BATCH / BM), dim3(256), 0, stream,
                       z, sb2, tb2, ws, fout, dvec);
}